// Round 8
// baseline (302.963 us; speedup 1.0000x reference)
//
#include <hip/hip_runtime.h>
#include <hip/hip_bf16.h>
#include <cstdint>
#include <cstddef>

#define BATCH 16
#define NROWS 4096
#define MROWS 2048
#define DDIM  256
#define NSPLIT 2
#define NTILES 32            // 8 chunks * 4 K-tiles(64)

typedef __attribute__((ext_vector_type(8))) short short8;
typedef __attribute__((ext_vector_type(4))) float f32x4;

static __device__ __forceinline__ unsigned cvtpk(float a, float b) {
  unsigned r;
  asm("v_cvt_pk_bf16_f32 %0, %1, %2" : "=v"(r) : "v"(a), "v"(b));
  return r;
}
#define SQ4(v) ((v).x*(v).x + (v).y*(v).y + (v).z*(v).z + (v).w*(v).w)

// LDS: A slots [par][ks] 16KB each at 0..64K; B at 64K..128K; norms after.
#define LDSA(P,K) (lds + (((P)*2+(K))<<14))
#define LDSB(P,K) (lds + 65536 + (((P)*2+(K))<<14))

static __device__ __forceinline__ short8 ldsfrag(const char* slot, int row, int ps) {
  return *(const short8*)(slot + row * 64 + (ps << 4));
}

// ---------------- Kernel 1: fused normalize+cast+GEMM+column-max ----------------
__global__ void __launch_bounds__(512, 2) maxsim_fused(
    const float* __restrict__ X1,   // [BATCH][NROWS][DDIM] fp32
    const float* __restrict__ X2,   // [BATCH][MROWS][DDIM] fp32
    float* __restrict__ partials)   // [NSPLIT][BATCH][MROWS]
{
  __shared__ __align__(16) char lds[133120];
  float* norm2a = (float*)(lds + 131072);   // [256] per-chunk A row sumsq
  float* norm2b = (float*)(lds + 132096);   // [256] B col sumsq (chunk0 pass)

  const int t = threadIdx.x;
  const int lane = t & 63;
  const int w = t >> 6;
  const int wr = w >> 2, wc = w & 3;
  const int lrow = lane & 15;
  const int pslot = (lane >> 4) ^ ((lane >> 1) & 3);

  // XCD-aware bijective swizzle: 256 blocks, XCD k owns batches {2k,2k+1}.
  const int hw = blockIdx.x;
  const int logical = (hw & 7) * 32 + (hw >> 3);
  const int mt = logical & 7;
  const int grp = logical >> 3;
  const int sp = grp & 1;
  const int bb = grp >> 1;

  const int m0 = mt * 256;
  const int nbase = sp * (NROWS / NSPLIT);

  const float* Af = X1 + ((size_t)bb * NROWS + nbase) * DDIM;
  const float* Bf = X2 + ((size_t)bb * MROWS + m0) * DDIM;

  // staging thread mapping: rows r0,r1; k-quarter kq (8 elems)
  const int rl = lane >> 2;
  const int kq = lane & 3;
  const int r0 = (w*2+0)*16 + rl;
  const int r1 = (w*2+1)*16 + rl;
  const float* pA0 = Af + (size_t)r0 * DDIM + kq*8;
  const float* pA1 = Af + (size_t)r1 * DDIM + kq*8;
  const float* pB0 = Bf + (size_t)r0 * DDIM + kq*8;
  const float* pB1 = Bf + (size_t)r1 * DDIM + kq*8;
  const int pphys = kq ^ ((rl >> 1) & 3);          // write-side swizzle (matches pslot)
  const int lw0 = (w*2+0)*1024 + rl*64 + pphys*16;
  const int lw1 = lw0 + 1024;

  #define DECL_SET(N) float4 N##0, N##1, N##2, N##3
  #define ISSUE(N, PX0, PX1, OFF) do { \
    N##0 = *(const float4*)((PX0) + (OFF));     \
    N##1 = *(const float4*)((PX0) + (OFF) + 4); \
    N##2 = *(const float4*)((PX1) + (OFF));     \
    N##3 = *(const float4*)((PX1) + (OFF) + 4); } while (0)
  #define WRITE(N, SLOT, A0_, A1_, DOACC) do { \
    if (DOACC) { A0_ += SQ4(N##0) + SQ4(N##1); A1_ += SQ4(N##2) + SQ4(N##3); } \
    *(uint4*)((SLOT) + lw0) = make_uint4(cvtpk((N##0).x,(N##0).y), cvtpk((N##0).z,(N##0).w), \
                                         cvtpk((N##1).x,(N##1).y), cvtpk((N##1).z,(N##1).w)); \
    *(uint4*)((SLOT) + lw1) = make_uint4(cvtpk((N##2).x,(N##2).y), cvtpk((N##2).z,(N##2).w), \
                                         cvtpk((N##3).x,(N##3).y), cvtpk((N##3).z,(N##3).w)); \
  } while (0)

  DECL_SET(p0); DECL_SET(p1); DECL_SET(p2); DECL_SET(p3);
  DECL_SET(s0); DECL_SET(s1); DECL_SET(s2); DECL_SET(s3);
  float acc_a0 = 0.f, acc_a1 = 0.f, acc_b0 = 0.f, acc_b1 = 0.f;

  // ---- Prologue: issue T0.{A0,B0,A1,B1} + T1.{A0,B0}; write T0's 4 units.
  ISSUE(p0, pA0, pA1, 0);
  ISSUE(p1, pB0, pB1, 0);
  ISSUE(p2, pA0, pA1, 32);
  ISSUE(p3, pB0, pB1, 32);
  ISSUE(s2, pA0, pA1, 64);    // T1.A0 -> written loop ph0
  ISSUE(s3, pB0, pB1, 64);    // T1.B0 -> written loop ph1
  WRITE(p0, LDSA(0,0), acc_a0, acc_a1, 1);
  WRITE(p1, LDSB(0,0), acc_b0, acc_b1, 1);
  WRITE(p2, LDSA(0,1), acc_a0, acc_a1, 1);
  WRITE(p3, LDSB(0,1), acc_b0, acc_b1, 1);
  asm volatile("s_waitcnt lgkmcnt(0)" ::: "memory");
  asm volatile("s_barrier" ::: "memory");

  f32x4 acc[8][4] = {};
  short8 afr[4], bfr[4];
  float cm[4] = {-INFINITY, -INFINITY, -INFINITY, -INFINITY};

  #define RD_B(P,K) do { _Pragma("unroll") \
    for (int nj = 0; nj < 4; ++nj) \
      bfr[nj] = ldsfrag(LDSB(P,K), wc*64 + nj*16 + lrow, pslot); } while (0)
  #define RD_A(P,K,MO) do { _Pragma("unroll") \
    for (int mi = 0; mi < 4; ++mi) \
      afr[mi] = ldsfrag(LDSA(P,K), wr*128 + ((MO)+mi)*16 + lrow, pslot); } while (0)
  #define SYNC do { asm volatile("s_waitcnt lgkmcnt(0)" ::: "memory"); \
                    asm volatile("s_barrier" ::: "memory"); } while (0)
  #define BAR  asm volatile("s_barrier" ::: "memory")
  #define MF(MIOFF) do { __builtin_amdgcn_s_setprio(1); \
    _Pragma("unroll") for (int mi = 0; mi < 4; ++mi) \
      _Pragma("unroll") for (int nj = 0; nj < 4; ++nj) \
        acc[(MIOFF)+mi][nj] = __builtin_amdgcn_mfma_f32_16x16x32_bf16( \
            afr[mi], bfr[nj], acc[(MIOFF)+mi][nj], 0, 0, 0); \
    __builtin_amdgcn_s_setprio(0); } while (0)

  #define FLUSH_A do { \
    float v0 = acc_a0; v0 += __shfl_xor(v0, 1, 64); v0 += __shfl_xor(v0, 2, 64); \
    float v1 = acc_a1; v1 += __shfl_xor(v1, 1, 64); v1 += __shfl_xor(v1, 2, 64); \
    if ((lane & 3) == 0) { norm2a[r0] = v0; norm2a[r1] = v1; } \
    acc_a0 = 0.f; acc_a1 = 0.f; } while (0)
  #define FLUSH_B do { \
    float v0 = acc_b0; v0 += __shfl_xor(v0, 1, 64); v0 += __shfl_xor(v0, 2, 64); \
    float v1 = acc_b1; v1 += __shfl_xor(v1, 1, 64); v1 += __shfl_xor(v1, 2, 64); \
    if ((lane & 3) == 0) { norm2b[r0] = v0; norm2b[r1] = v1; } } while (0)
  #define FOLD do { _Pragma("unroll") \
    for (int mi = 0; mi < 8; ++mi) { \
      f32x4 n2 = *(const f32x4*)(norm2a + wr*128 + mi*16 + (lane>>4)*4); \
      f32x4 rq; \
      _Pragma("unroll") for (int j = 0; j < 4; ++j) \
        rq[j] = rsqrtf(fmaxf(n2[j], 1e-24f)); \
      _Pragma("unroll") for (int nj = 0; nj < 4; ++nj) { \
        float m_ = fmaxf(fmaxf(acc[mi][nj][0]*rq[0], acc[mi][nj][1]*rq[1]), \
                         fmaxf(acc[mi][nj][2]*rq[2], acc[mi][nj][3]*rq[3])); \
        cm[nj] = fmaxf(cm[nj], m_); \
        acc[mi][nj] = (f32x4){0.f, 0.f, 0.f, 0.f}; } } } while (0)

  // Phase schedule per tile T (issue u=4T+ph+6, write u=4T+ph+4):
  //  ph0: rd B/A(ks0,lo); issue (T+1).A1; write (T+1).A0
  //  ph1: rd A(ks0,hi);   issue (T+1).B1; write (T+1).B0
  //  ph2: rd B/A(ks1,lo); issue (T+2).A0; write (T+1).A1  [+flush A @ T%4==2]
  //  ph3: rd A(ks1,hi);   issue (T+2).B0; write (T+1).B1  [+flush B @ T==2; fold @ T%4==3]
  #define TILE(PAR, NPAR, TT) do { \
    const int t1 = (TT) + 1, t2 = (TT) + 2; \
    const int oA1 = (t1 >> 2) * 256 * DDIM + (t1 & 3) * 64 + 32; \
    const int oB1 = (t1 & 3) * 64 + 32; \
    const int oA2 = (t2 >> 2) * 256 * DDIM + (t2 & 3) * 64; \
    const int oB2 = (t2 & 3) * 64; \
    const bool wg = (TT) < 31, ig = (TT) < 30; \
    const bool bacc = (TT) <= 2; \
    /* ph0 */ \
    RD_B(PAR,0); RD_A(PAR,0,0); \
    if (wg) { ISSUE(s0, pA0, pA1, oA1); WRITE(s2, LDSA(NPAR,0), acc_a0, acc_a1, 1); } \
    SYNC; MF(0); BAR; \
    /* ph1 */ \
    RD_A(PAR,0,4); \
    if (wg) { ISSUE(s1, pB0, pB1, oB1); WRITE(s3, LDSB(NPAR,0), acc_b0, acc_b1, bacc); } \
    SYNC; MF(4); BAR; \
    /* ph2 */ \
    RD_B(PAR,1); RD_A(PAR,1,0); \
    if (ig) ISSUE(s2, pA0, pA1, oA2); \
    if (wg) { WRITE(s0, LDSA(NPAR,1), acc_a0, acc_a1, 1); \
              if (((TT) & 3) == 2) FLUSH_A; } \
    SYNC; MF(0); BAR; \
    /* ph3 */ \
    RD_A(PAR,1,4); \
    if (ig) ISSUE(s3, pB0, pB1, oB2); \
    if (wg) { WRITE(s1, LDSB(NPAR,1), acc_b0, acc_b1, bacc); \
              if ((TT) == 2) FLUSH_B; } \
    SYNC; MF(4); \
    if (((TT) & 3) == 3) FOLD; \
    BAR; \
  } while (0)

  for (int g2 = 0; g2 < 16; ++g2) {
    TILE(0, 1, 2 * g2);
    TILE(1, 0, 2 * g2 + 1);
  }
  #undef TILE

  // ---- Epilogue: cross-wave column max, apply 1/|b_m|, write partials.
  asm volatile("s_waitcnt lgkmcnt(0)" ::: "memory");
  asm volatile("s_barrier" ::: "memory");
  float* cmax = (float*)lds;   // [2][256]
  #pragma unroll
  for (int nj = 0; nj < 4; ++nj) {
    cm[nj] = fmaxf(cm[nj], __shfl_xor(cm[nj], 16, 64));
    cm[nj] = fmaxf(cm[nj], __shfl_xor(cm[nj], 32, 64));
  }
  if (lane < 16) {
    #pragma unroll
    for (int nj = 0; nj < 4; ++nj)
      cmax[wr * 256 + wc * 64 + nj * 16 + lane] = cm[nj];
  }
  __syncthreads();
  if (t < 256) {
    float v = fmaxf(cmax[t], cmax[256 + t]) * rsqrtf(fmaxf(norm2b[t], 1e-24f));
    partials[((size_t)sp * BATCH + bb) * MROWS + m0 + t] = v;
  }
}

// ---------------- Kernel 2: per-batch loss ----------------
__global__ void __launch_bounds__(256) batch_loss(
    const float* __restrict__ partials, const float* __restrict__ y,
    float* __restrict__ bloss) {
  __shared__ float red[4];
  const int b = blockIdx.x;
  const int t = threadIdx.x;
  const int lane = t & 63;
  const int w = t >> 6;
  float s = 0.0f;
  for (int m = t; m < MROWS; m += 256) {
    float v = partials[(size_t)b * MROWS + m];
    #pragma unroll
    for (int sp = 1; sp < NSPLIT; ++sp)
      v = fmaxf(v, partials[((size_t)sp * BATCH + b) * MROWS + m]);
    s += v;
  }
  #pragma unroll
  for (int o = 32; o >= 1; o >>= 1) s += __shfl_xor(s, o, 64);
  if (lane == 0) red[w] = s;
  __syncthreads();
  if (t == 0) {
    float sum = red[0] + red[1] + red[2] + red[3];
    float mean = sum / (float)MROWS;
    float yb = y[b];
    float d = mean - yb;
    bloss[b] = d * d;   // Y_SCALE == 1.0
  }
}

// ---------------- Kernel 3: combine per-batch losses ----------------
__global__ void __launch_bounds__(64) final_sum(
    const float* __restrict__ bloss, float* __restrict__ out) {
  const int t = threadIdx.x;
  float v = (t < BATCH) ? bloss[t] : 0.0f;
  #pragma unroll
  for (int o = 32; o >= 1; o >>= 1) v += __shfl_xor(v, o, 64);
  if (t == 0) out[0] = v;
}

extern "C" void kernel_launch(void* const* d_in, const int* in_sizes, int n_in,
                              void* d_out, int out_size, void* d_ws, size_t ws_size,
                              hipStream_t stream) {
  const float* x1 = (const float*)d_in[0];
  const float* x2 = (const float*)d_in[1];
  const float* y  = (const float*)d_in[2];
  float* out = (float*)d_out;

  float* partials = (float*)d_ws;
  float* bloss = partials + (size_t)NSPLIT * BATCH * MROWS;

  maxsim_fused<<<BATCH * 8 * NSPLIT, 512, 0, stream>>>(x1, x2, partials);
  batch_loss<<<BATCH, 256, 0, stream>>>(partials, y, bloss);
  final_sum<<<1, 64, 0, stream>>>(bloss, out);
}

// Round 9
// 86.968 us; speedup vs baseline: 3.4836x; 3.4836x over previous
//
#include <hip/hip_runtime.h>
#include <hip/hip_bf16.h>
#include <cstdint>
#include <cstddef>

#define BATCH 16
#define NROWS 4096
#define MROWS 2048
#define DDIM  256
#define NSPLIT 2
#define NCHUNKS 8            // (NROWS/NSPLIT)/256

typedef __attribute__((ext_vector_type(8))) short short8;
typedef __attribute__((ext_vector_type(4))) float f32x4;

static __device__ __forceinline__ unsigned short f2bf(float f) {
  unsigned int x = __float_as_uint(f);
  x += 0x7fffu + ((x >> 16) & 1u);
  return (unsigned short)(x >> 16);
}

// ---------------- Kernel 1: row L2-normalize + bf16 cast ----------------
__global__ void __launch_bounds__(256) norm_cast(
    const float* __restrict__ x1, const float* __restrict__ x2,
    unsigned short* __restrict__ aout, unsigned short* __restrict__ bout,
    unsigned* __restrict__ counter) {
  if (blockIdx.x == 0 && threadIdx.x == 0) *counter = 0u;  // for loss kernel
  const int wid  = threadIdx.x >> 6;
  const int lane = threadIdx.x & 63;
  const long long row = (long long)blockIdx.x * 4 + wid;
  const long long R1 = (long long)BATCH * NROWS;
  const long long R2 = (long long)BATCH * MROWS;
  if (row >= R1 + R2) return;
  const float* src; unsigned short* dst;
  if (row < R1) { src = x1 + row * DDIM; dst = aout + row * DDIM; }
  else { long long r2 = row - R1; src = x2 + r2 * DDIM; dst = bout + r2 * DDIM; }
  float4 v = ((const float4*)src)[lane];
  float ss = v.x*v.x + v.y*v.y + v.z*v.z + v.w*v.w;
  #pragma unroll
  for (int o = 32; o >= 1; o >>= 1) ss += __shfl_xor(ss, o, 64);
  float n = sqrtf(ss);
  float sc = 1.0f / fmaxf(n, 1e-12f);
  ushort4 o;
  o.x = f2bf(v.x * sc); o.y = f2bf(v.y * sc);
  o.z = f2bf(v.z * sc); o.w = f2bf(v.w * sc);
  ((ushort4*)dst)[lane] = o;
}

// ---------------- Kernel 2: 8-phase 256x256 fused GEMM + column-max ----------------
typedef __attribute__((address_space(1))) const void gas_t;
typedef __attribute__((address_space(3))) void las_t;
#define GLL16(g, l) __builtin_amdgcn_global_load_lds((gas_t*)(g), (las_t*)(l), 16, 0, 0)

// LDS slots: [256 rows][32 k] bf16 = 16 KB each. A: parity x ks, then B.
#define LDSA(P,K) (lds + (((P)*2+(K))<<14))
#define LDSB(P,K) (lds + 65536 + (((P)*2+(K))<<14))

static __device__ __forceinline__ short8 ldsfrag(const char* slot, int row, int pslot) {
  return *(const short8*)(slot + row * 64 + (pslot << 4));
}

__global__ void __launch_bounds__(512, 1) maxsim_gemm8(
    const unsigned short* __restrict__ A,   // [BATCH][NROWS][DDIM]
    const unsigned short* __restrict__ Bm,  // [BATCH][MROWS][DDIM]
    float* __restrict__ partials)           // [NSPLIT][BATCH][MROWS]
{
  __shared__ __align__(16) char lds[131072];

  const int t = threadIdx.x;
  const int lane = t & 63;
  const int w = t >> 6;
  const int wr = w >> 2;     // n-half (wave owns 128 rows)
  const int wc = w & 3;      // m-quarter (wave owns 64 cols)
  const int lrow = lane & 15;
  const int pslot = (lane >> 4) ^ ((lane >> 1) & 3);  // swizzled 16B slot for frag reads

  // XCD-aware bijective swizzle: 256 blocks, XCD k owns batches {2k,2k+1}.
  const int hw = blockIdx.x;
  const int logical = (hw & 7) * 32 + (hw >> 3);
  const int mt = logical & 7;
  const int grp = logical >> 3;
  const int sp = grp & 1;
  const int bb = grp >> 1;

  const int m0 = mt * 256;
  const int nbase = sp * (NROWS / NSPLIT);

  const unsigned short* Aba = A  + (size_t)bb * NROWS * DDIM;
  const unsigned short* Bba = Bm + ((size_t)bb * MROWS + m0) * DDIM;

  // Per-thread staging bases (hoisted): chunk c = w*2+i covers rows c*16..+15.
  // Source k-slot pre-swizzled: sphys = (lane&3) ^ ((lane>>3)&3).
  const int r0 = (w * 2 + 0) * 16 + (lane >> 2);
  const int r1 = (w * 2 + 1) * 16 + (lane >> 2);
  const int sph8 = (((lane & 3) ^ ((lane >> 3) & 3)) << 3);
  const unsigned short* sA0 = Aba + (size_t)r0 * DDIM + sph8;
  const unsigned short* sA1 = Aba + (size_t)r1 * DDIM + sph8;
  const unsigned short* sB0 = Bba + (size_t)r0 * DDIM + sph8;
  const unsigned short* sB1 = Bba + (size_t)r1 * DDIM + sph8;
  const int l0 = (w * 2 + 0) * 1024 + lane * 16;   // slot-relative LDS dest
  const int l1 = (w * 2 + 1) * 1024 + lane * 16;

  #define STAGE_A(SLOT, OFF) do { \
    GLL16(sA0 + (OFF), (SLOT) + l0); GLL16(sA1 + (OFF), (SLOT) + l1); } while (0)
  #define STAGE_B(SLOT, OFF) do { \
    GLL16(sB0 + (OFF), (SLOT) + l0); GLL16(sB1 + (OFF), (SLOT) + l1); } while (0)

  f32x4 acc[8][4] = {};
  short8 afr[4], bfr[4];
  float cm[4] = {-INFINITY, -INFINITY, -INFINITY, -INFINITY};

  // ---- Prologue: tile0 (4 halves) + tile1's {B ks0, A ks0, B ks1}.
  STAGE_A(LDSA(0,0), nbase * DDIM + 0);
  STAGE_B(LDSB(0,0), 0);
  STAGE_A(LDSA(0,1), nbase * DDIM + 32);
  STAGE_B(LDSB(0,1), 32);
  STAGE_B(LDSB(1,0), 64);
  STAGE_A(LDSA(1,0), nbase * DDIM + 64);
  STAGE_B(LDSB(1,1), 96);
  asm volatile("s_waitcnt vmcnt(6)" ::: "memory");   // tile0 fully landed
  __builtin_amdgcn_s_barrier();

  // Phase (m201 order): reads; stage; BARRIER; lgkmcnt(0) [drain overlaps
  // barrier wait across waves]; pinned MFMA; [ph3: vmcnt(6) under-MFMA]; BARRIER.
  #define PHASE(RDB, BSLOT, ASLOT, MIOFF, STAGE_STMT, VMW) do {                    \
    if (RDB) {                                                                     \
      _Pragma("unroll")                                                            \
      for (int nj = 0; nj < 4; ++nj)                                               \
        bfr[nj] = ldsfrag(BSLOT, wc*64 + nj*16 + lrow, pslot);                     \
    }                                                                              \
    _Pragma("unroll")                                                              \
    for (int mi = 0; mi < 4; ++mi)                                                 \
      afr[mi] = ldsfrag(ASLOT, wr*128 + ((MIOFF)+mi)*16 + lrow, pslot);            \
    STAGE_STMT;                                                                    \
    __builtin_amdgcn_s_barrier();                                                  \
    asm volatile("s_waitcnt lgkmcnt(0)" ::: "memory");                             \
    __builtin_amdgcn_sched_barrier(0);                                             \
    __builtin_amdgcn_s_setprio(1);                                                 \
    _Pragma("unroll")                                                              \
    for (int mi = 0; mi < 4; ++mi)                                                 \
      _Pragma("unroll")                                                            \
      for (int nj = 0; nj < 4; ++nj)                                               \
        acc[(MIOFF)+mi][nj] = __builtin_amdgcn_mfma_f32_16x16x32_bf16(             \
            afr[mi], bfr[nj], acc[(MIOFF)+mi][nj], 0, 0, 0);                       \
    __builtin_amdgcn_s_setprio(0);                                                 \
    if (VMW) asm volatile("s_waitcnt vmcnt(6)" ::: "memory");                      \
    __builtin_amdgcn_s_barrier();                                                  \
  } while (0)

  for (int nc = 0; nc < NCHUNKS; ++nc) {
    #pragma unroll
    for (int kt = 0; kt < 4; ++kt) {
      const int par  = kt & 1;
      const int npar = par ^ 1;
      // Stage ledger: ph0 completes tile T+1 (A ks1); ph1-3 issue tile T+2's
      // {B ks0, A ks0, B ks1}. vmcnt(6) at ph3 => tile T+1 fully landed.
      const int ncA1 = (kt < 3) ? nc : ((nc + 1) & (NCHUNKS - 1));  // T+1's chunk
      const int kA1  = ((kt + 1) & 3) * 64 + 32;
      const int ncT2 = (kt < 2) ? nc : ((nc + 1) & (NCHUNKS - 1));  // T+2's chunk
      const int kT2  = ((kt + 2) & 3) * 64;
      const int offA1 = (nbase + ncA1 * 256) * DDIM + kA1;
      const int offA2 = (nbase + ncT2 * 256) * DDIM + kT2;

      PHASE(1, LDSB(par,0), LDSA(par,0), 0, STAGE_A(LDSA(npar,1), offA1), 0);
      PHASE(0, LDSB(par,0), LDSA(par,0), 4, STAGE_B(LDSB(par,0), kT2),    0);
      PHASE(1, LDSB(par,1), LDSA(par,1), 0, STAGE_A(LDSA(par,0), offA2),  0);
      PHASE(0, LDSB(par,1), LDSA(par,1), 4, STAGE_B(LDSB(par,1), kT2+32), 1);
    }
    // fold this n-chunk's C tile into running column max; reset acc
    #pragma unroll
    for (int nj = 0; nj < 4; ++nj) {
      float v = cm[nj];
      #pragma unroll
      for (int mi = 0; mi < 8; ++mi) {
        v = fmaxf(v, acc[mi][nj][0]);
        v = fmaxf(v, acc[mi][nj][1]);
        v = fmaxf(v, acc[mi][nj][2]);
        v = fmaxf(v, acc[mi][nj][3]);
        acc[mi][nj] = (f32x4){0.0f, 0.0f, 0.0f, 0.0f};
      }
      cm[nj] = v;
    }
  }
  #undef PHASE

  // ---- Epilogue: drain DMA, reduce max across lanes/waves, write partials
  asm volatile("s_waitcnt vmcnt(0)" ::: "memory");
  __builtin_amdgcn_s_barrier();
  float* cmax = (float*)lds;   // [2][256]
  #pragma unroll
  for (int nj = 0; nj < 4; ++nj) {
    cm[nj] = fmaxf(cm[nj], __shfl_xor(cm[nj], 16, 64));
    cm[nj] = fmaxf(cm[nj], __shfl_xor(cm[nj], 32, 64));
  }
  if (lane < 16) {
    #pragma unroll
    for (int nj = 0; nj < 4; ++nj)
      cmax[wr * 256 + wc * 64 + nj * 16 + lane] = cm[nj];
  }
  __syncthreads();
  if (t < 256) {
    float v = fmaxf(cmax[t], cmax[256 + t]);
    partials[((size_t)sp * BATCH + bb) * MROWS + m0 + t] = v;
  }
}

// ---------------- Kernel 3: per-batch loss + last-block final sum ----------------
__global__ void __launch_bounds__(256) batch_loss_final(
    const float* __restrict__ partials, const float* __restrict__ y,
    float* __restrict__ out, float* __restrict__ bloss,
    unsigned* __restrict__ counter) {
  __shared__ float red[4];
  __shared__ bool amlast;
  const int b = blockIdx.x;
  const int t = threadIdx.x;
  const int lane = t & 63;
  const int w = t >> 6;
  float s = 0.0f;
  for (int m = t; m < MROWS; m += 256) {
    float v = partials[(size_t)b * MROWS + m];
    #pragma unroll
    for (int sp = 1; sp < NSPLIT; ++sp)
      v = fmaxf(v, partials[((size_t)sp * BATCH + b) * MROWS + m]);
    s += v;
  }
  #pragma unroll
  for (int o = 32; o >= 1; o >>= 1) s += __shfl_xor(s, o, 64);
  if (lane == 0) red[w] = s;
  __syncthreads();
  if (t == 0) {
    float sum = red[0] + red[1] + red[2] + red[3];
    float mean = sum / (float)MROWS;
    float d = mean - y[b];
    bloss[b] = d * d;   // Y_SCALE == 1.0
    __threadfence();
    unsigned old = atomicAdd(counter, 1u);
    amlast = (old == BATCH - 1);
  }
  __syncthreads();
  if (amlast && t == 0) {
    __threadfence();
    float tot = 0.0f;
    #pragma unroll
    for (int i = 0; i < BATCH; ++i) tot += bloss[i];
    out[0] = tot;
    *counter = 0;   // reset for next replay (deterministic across calls)
  }
}

extern "C" void kernel_launch(void* const* d_in, const int* in_sizes, int n_in,
                              void* d_out, int out_size, void* d_ws, size_t ws_size,
                              hipStream_t stream) {
  const float* x1 = (const float*)d_in[0];
  const float* x2 = (const float*)d_in[1];
  const float* y  = (const float*)d_in[2];
  float* out = (float*)d_out;

  unsigned short* aBF = (unsigned short*)d_ws;
  unsigned short* bBF = aBF + (size_t)BATCH * NROWS * DDIM;
  float* partials = (float*)(bBF + (size_t)BATCH * MROWS * DDIM);
  float* bloss = partials + (size_t)NSPLIT * BATCH * MROWS;
  unsigned* counter = (unsigned*)(bloss + BATCH);

  const int totRows = BATCH * (NROWS + MROWS);
  norm_cast<<<(totRows + 3) / 4, 256, 0, stream>>>(x1, x2, aBF, bBF, counter);
  maxsim_gemm8<<<BATCH * 8 * NSPLIT, 512, 0, stream>>>(aBF, bBF, partials);
  batch_loss_final<<<BATCH, 256, 0, stream>>>(partials, y, out, bloss, counter);
}